// Round 10
// baseline (459.645 us; speedup 1.0000x reference)
//
#include <hip/hip_runtime.h>
#include <hip/hip_bf16.h>

typedef _Float16 f16x8 __attribute__((ext_vector_type(8)));
typedef float f32x4  __attribute__((ext_vector_type(4)));
typedef unsigned short u16x4 __attribute__((ext_vector_type(4)));

#define T_STEPS 40
#define BATCH   256
#define S2LO    0.000244140625f   // 2^-12, exact

__device__ __forceinline__ unsigned short f2h_bits(float f) {
    union { _Float16 h; unsigned short u; } c; c.h = (_Float16)f; return c.u;
}

// norse LIF step, pinned to mul-then-add fp32 order.
__device__ __forceinline__ float lif_update(float inp, float& v, float& i, float vth) {
    float vd = __fadd_rn(v, __fmul_rn(0.1f, __fsub_rn(i, v)));
    float id = __fmul_rn(0.8f, i);
    float z  = (vd > vth) ? 1.0f : 0.0f;
    v = (vd > vth) ? 0.0f : vd;
    i = __fadd_rn(id, inp);
    return z;
}

__device__ __forceinline__ void llds16(const unsigned short* g, void* l) {
    __builtin_amdgcn_global_load_lds(
        (const __attribute__((address_space(1))) unsigned int*)g,
        (__attribute__((address_space(3))) unsigned int*)l, 16, 0, 0);
}

// ---------------------------------------------------------------------------
// Kernel 1: conv1 (fp32) + LIF0 + 2x2 avgpool, persistent over t.
// tid = oc*26 + pr (pool partner = adjacent lane); double-buffered x staging,
// ONE barrier/step; pooling via one __shfl_xor of 13 packed 2-bit sums.
// Output s0 u8 (pooled sum 0..4), row stride 4096: [pos169][ic24]+zero pad.
// ---------------------------------------------------------------------------
__global__ __launch_bounds__(576) void k_conv1(
    const float* __restrict__ x,             // [T,B,784] fp32
    const float* __restrict__ w1,            // [20,1,3,3] fp32
    unsigned char* __restrict__ s0)          // [T,B,4096] u8
{
    const int b   = blockIdx.x;
    const int tid = threadIdx.x;
    const bool active = tid < 520;
    const int oc = tid / 26;
    const int pr = tid % 26;

    __shared__ __align__(16) float xl[2][784];

    float wr[9];
    if (active) {
        #pragma unroll
        for (int j = 0; j < 9; ++j) wr[j] = w1[oc*9 + j];
    }
    float vs[26], is[26];
    #pragma unroll
    for (int p = 0; p < 26; ++p) { vs[p] = 0.f; is[p] = 0.f; }

    // prologue: stage t=0 into buffer 0
    if (tid < 196) {
        const float4* xs4 = (const float4*)(x + (size_t)(0*BATCH + b)*784);
        *(float4*)&xl[0][tid*4] = xs4[tid];
    }

    for (int t = 0; t < T_STEPS; ++t) {
        __syncthreads();   // staging of t complete; buffer (t+1)&1 free
        if (t + 1 < T_STEPS && tid < 196) {
            const float4* xs4 = (const float4*)(x + (size_t)((t+1)*BATCH + b)*784);
            *(float4*)&xl[(t+1)&1][tid*4] = xs4[tid];
        }
        const float* xc = xl[t&1];

        unsigned int packed = 0;
        if (active) {
            float acc[26];
            #pragma unroll
            for (int p = 0; p < 26; ++p) acc[p] = 0.f;
            #pragma unroll
            for (int kr = 0; kr < 3; ++kr) {
                float row[28];
                #pragma unroll
                for (int q = 0; q < 7; ++q)
                    *(float4*)&row[q*4] = *(const float4*)&xc[(pr+kr)*28 + q*4];
                #pragma unroll
                for (int kc = 0; kc < 3; ++kc) {
                    float w = wr[kr*3+kc];
                    #pragma unroll
                    for (int p = 0; p < 26; ++p) acc[p] += row[p+kc] * w;
                }
            }
            int zi[26];
            #pragma unroll
            for (int p = 0; p < 26; ++p) {
                float z = lif_update(acc[p], vs[p], is[p], 0.2f);
                zi[p] = (z > 0.5f) ? 1 : 0;
            }
            #pragma unroll
            for (int q = 0; q < 13; ++q)
                packed |= (unsigned int)(zi[2*q] + zi[2*q+1]) << (2*q);
        }
        unsigned int other = __shfl_xor((int)packed, 1);

        size_t base = (size_t)(t*BATCH + b) * 4096;
        if (active && (pr & 1) == 0) {
            int prow = pr >> 1;
            #pragma unroll
            for (int q = 0; q < 13; ++q) {
                unsigned int s = ((packed >> (2*q)) & 3u) + ((other >> (2*q)) & 3u);
                s0[base + (size_t)(prow*13 + q)*24 + oc] = (unsigned char)s;
            }
        }
        for (int s2 = tid; s2 < 716; s2 += 576) {
            if (s2 < 676) s0[base + (size_t)(s2 >> 2)*24 + 20 + (s2 & 3)] = 0;  // ic pad
            else          s0[base + 4056 + (s2 - 676)] = 0;                     // row tail
        }
    }
}

// ---------------------------------------------------------------------------
// Kernel 2: conv2 via fp16 MFMA, 2 blocks/sample (oc-split), double-buffered
// staging (u8 global->regs->fp16->ds_write_b128), one barrier/step. 2-plane
// weights (hi persistent in VGPR, scaled-lo from LDS) + LIF1 in VGPRs.
// z1 layout: oc-stride 124 -> aligned ushort4 stores.
// ---------------------------------------------------------------------------
__global__ __launch_bounds__(256, 2) void k_conv2(
    const unsigned char* __restrict__ s0,    // [T,B,4096] u8
    const float* __restrict__ w2,            // [50,20,3,3] fp32
    unsigned short* __restrict__ z1)         // [T,B,6208] fp16 spikes
{
    const int b    = blockIdx.x >> 1;
    const int half = blockIdx.x & 1;
    const int tid  = threadIdx.x;
    const int wv   = tid >> 6;
    const int lane = tid & 63;
    const int l15  = lane & 15;
    const int kg   = lane >> 4;
    const int wm   = wv;           // 4 m-waves x 32 pos

    __shared__ __align__(16) unsigned short w2h[32*232];
    __shared__ __align__(16) unsigned short w2m[32*232];
    __shared__ __align__(16) unsigned short sIn[2*4096];   // fp16 double buffer

    for (int s = tid; s < 32*232; s += 256) {
        int ocw = s / 232, kk = s % 232;
        int g = kk / 24, ic = kk % 24;
        int oc = half*32 + ocw;
        float val = 0.f;
        if (oc < 50 && g < 9 && ic < 20) val = w2[(oc*20 + ic)*9 + g];
        _Float16 h = (_Float16)val;
        float r1 = (val - (float)h) * 4096.0f;
        union { _Float16 h; unsigned short u; } ch, cm;
        ch.h = h; cm.h = (_Float16)r1;
        w2h[s] = ch.u;
        w2m[s] = cm.u;
    }

    f16x8 bfrH[2][7];
    int addrA[2][7];
    #pragma unroll
    for (int mt = 0; mt < 2; ++mt) {
        int pos = wm*32 + mt*16 + l15;
        #pragma unroll
        for (int kt = 0; kt < 7; ++kt) {
            int k = kt*32 + kg*8;
            int g = k / 24, o = k - g*24;
            if (pos <= 120 && g <= 8) {
                int in_idx = pos + 2*(pos/11) + 13*(g/3) + (g % 3);
                addrA[mt][kt] = in_idx*48 + o*2;
            } else addrA[mt][kt] = 8128;   // elem 4064: zeroed tail
        }
    }

    // stage t=0 into buffer 0 (u8 -> fp16*0.25, exact)
    {
        const unsigned char* srow = s0 + (size_t)(0*BATCH + b)*4096;
        uint4 raw = *(const uint4*)(srow + tid*16);
        unsigned short hv[16];
        #pragma unroll
        for (int w = 0; w < 4; ++w) {
            unsigned int u = ((const unsigned int*)&raw)[w];
            #pragma unroll
            for (int j = 0; j < 4; ++j)
                hv[w*4+j] = f2h_bits(0.25f * (float)((u >> (8*j)) & 0xFFu));
        }
        unsigned short* dst = sIn + tid*16;
        *(f16x8*)dst       = *(const f16x8*)&hv[0];
        *(f16x8*)(dst + 8) = *(const f16x8*)&hv[8];
    }
    __syncthreads();   // weights + t=0 staging visible

    #pragma unroll
    for (int nt = 0; nt < 2; ++nt) {
        int n = nt*16 + l15;
        #pragma unroll
        for (int kt = 0; kt < 7; ++kt)
            bfrH[nt][kt] = *(const f16x8*)&w2h[n*232 + kt*32 + kg*8];
    }

    float vst[2][2][4], ist[2][2][4];
    #pragma unroll
    for (int mt = 0; mt < 2; ++mt)
        #pragma unroll
        for (int nt = 0; nt < 2; ++nt)
            #pragma unroll
            for (int r = 0; r < 4; ++r) { vst[mt][nt][r] = 0.f; ist[mt][nt][r] = 0.f; }

    const f32x4 zero4 = {0.f, 0.f, 0.f, 0.f};

    for (int t = 0; t < T_STEPS; ++t) {
        if (t > 0) __syncthreads();

        uint4 raw;
        if (t + 1 < T_STEPS)
            raw = *(const uint4*)(s0 + (size_t)((t+1)*BATCH + b)*4096 + tid*16);

        const char* curB = (const char*)(sIn + (t&1)*4096);

        f32x4 acch[2][2], accl[2][2];
        #pragma unroll
        for (int mt = 0; mt < 2; ++mt)
            #pragma unroll
            for (int nt = 0; nt < 2; ++nt) { acch[mt][nt] = zero4; accl[mt][nt] = zero4; }

        #pragma unroll
        for (int kt = 0; kt < 7; ++kt) {
            f16x8 bm[2];
            #pragma unroll
            for (int nt = 0; nt < 2; ++nt) {
                int n = nt*16 + l15, k = kt*32 + kg*8;
                bm[nt] = *(const f16x8*)&w2m[n*232 + k];
            }
            #pragma unroll
            for (int mt = 0; mt < 2; ++mt) {
                f16x8 a = *(const f16x8*)(curB + addrA[mt][kt]);
                #pragma unroll
                for (int nt = 0; nt < 2; ++nt) {
                    acch[mt][nt] = __builtin_amdgcn_mfma_f32_16x16x32_f16(
                        a, bfrH[nt][kt], acch[mt][nt], 0, 0, 0);
                    accl[mt][nt] = __builtin_amdgcn_mfma_f32_16x16x32_f16(
                        a, bm[nt], accl[mt][nt], 0, 0, 0);
                }
            }
        }

        size_t rowoff = (size_t)(t*BATCH + b) * 6208;
        #pragma unroll
        for (int mt = 0; mt < 2; ++mt) {
            int posb = wm*32 + mt*16 + kg*4;
            #pragma unroll
            for (int nt = 0; nt < 2; ++nt) {
                int ocn = half*32 + nt*16 + l15;
                u16x4 pack;
                #pragma unroll
                for (int r = 0; r < 4; ++r) {
                    float inp = __fadd_rn(acch[mt][nt][r], __fmul_rn(S2LO, accl[mt][nt][r]));
                    float z = lif_update(inp, vst[mt][nt][r], ist[mt][nt][r], 0.2f);
                    int pos = posb + r;
                    pack[r] = (pos <= 120 && z > 0.5f) ? (unsigned short)0x3C00 : (unsigned short)0;
                }
                if (ocn < 50 && posb < 121)
                    *(u16x4*)(z1 + rowoff + ocn*124 + posb) = pack;
            }
        }
        if (half == 0 && tid < 8) z1[rowoff + 6200 + tid] = 0;

        if (t + 1 < T_STEPS) {
            unsigned short hv[16];
            #pragma unroll
            for (int w = 0; w < 4; ++w) {
                unsigned int u = ((const unsigned int*)&raw)[w];
                #pragma unroll
                for (int j = 0; j < 4; ++j)
                    hv[w*4+j] = f2h_bits(0.25f * (float)((u >> (8*j)) & 0xFFu));
            }
            unsigned short* dst = sIn + ((t+1)&1)*4096 + tid*16;
            *(f16x8*)dst       = *(const f16x8*)&hv[0];
            *(f16x8*)(dst + 8) = *(const f16x8*)&hv[8];
        }
    }
}

// ---------------------------------------------------------------------------
// MFMA GEMM (fp16), m97 2-buffer, global_load_lds w16, XOR-swizzled LDS.
// blockIdx.z selects weight plane. 128x128 tile, BK=64.
// ---------------------------------------------------------------------------
__global__ __launch_bounds__(256, 3) void k_gemm(
    const unsigned short* __restrict__ A,
    const unsigned short* __restrict__ B0,
    float* __restrict__ C0,
    int Kp, int kiters, int ldc, int nstore,
    size_t strideB, size_t strideC)
{
    __shared__ __align__(16) unsigned short As[128*64];
    __shared__ __align__(16) unsigned short Bs[128*64];
    const unsigned short* B = B0 + (size_t)blockIdx.z * strideB;
    float* C = C0 + (size_t)blockIdx.z * strideC;

    const int tid  = threadIdx.x;
    const int lane = tid & 63;
    const int wv   = tid >> 6;
    const int wm   = wv & 1, wn = wv >> 1;
    const int l15  = lane & 15, kg = lane >> 4;
    const int mbase = blockIdx.x * 128;
    const int nbase = blockIdx.y * 128;

    const f32x4 zero4 = {0.f, 0.f, 0.f, 0.f};
    f32x4 acc[4][4];
    #pragma unroll
    for (int mt = 0; mt < 4; ++mt)
        #pragma unroll
        for (int nt = 0; nt < 4; ++nt) acc[mt][nt] = zero4;

    const int rowA = tid >> 3;                        // 0..31
    const int sw   = (((tid & 7) ^ (rowA & 7))) * 8;  // xor-swizzled chunk (elems)
    char* ldsA = (char*)As + (size_t)wv*1024;
    char* ldsB = (char*)Bs + (size_t)wv*1024;

    for (int ki = 0; ki < kiters; ++ki) {
        int kb = ki * 64;
        #pragma unroll
        for (int c = 0; c < 4; ++c) {
            int row = c*32 + rowA;
            llds16(A + (size_t)(mbase + row)*Kp + kb + sw, ldsA + c*4096);
            llds16(B + (size_t)(nbase + row)*Kp + kb + sw, ldsB + c*4096);
        }
        __syncthreads();
        #pragma unroll
        for (int kt = 0; kt < 2; ++kt) {
            f16x8 bfv[4], afv[4];
            #pragma unroll
            for (int nt = 0; nt < 4; ++nt) {
                int rb = wn*64 + nt*16 + l15;
                int ch = ((kt*4 + kg) ^ (rb & 7)) * 8;
                bfv[nt] = *(const f16x8*)&Bs[rb*64 + ch];
            }
            #pragma unroll
            for (int mt = 0; mt < 4; ++mt) {
                int ra = wm*64 + mt*16 + l15;
                int ch = ((kt*4 + kg) ^ (ra & 7)) * 8;
                afv[mt] = *(const f16x8*)&As[ra*64 + ch];
            }
            #pragma unroll
            for (int mt = 0; mt < 4; ++mt)
                #pragma unroll
                for (int nt = 0; nt < 4; ++nt)
                    acc[mt][nt] = __builtin_amdgcn_mfma_f32_16x16x32_f16(
                        afv[mt], bfv[nt], acc[mt][nt], 0, 0, 0);
        }
        __syncthreads();
    }

    #pragma unroll
    for (int mt = 0; mt < 4; ++mt) {
        int m0 = mbase + wm*64 + mt*16 + kg*4;
        #pragma unroll
        for (int nt = 0; nt < 4; ++nt) {
            int n = nbase + wn*64 + nt*16 + l15;
            if (n < nstore) {
                #pragma unroll
                for (int r = 0; r < 4; ++r)
                    C[(size_t)(m0 + r)*ldc + n] = acc[mt][nt][r];
            }
        }
    }
}

// Pack fp32 weights [N,K] -> zero-padded fp16 planes: hi=fp16(w), lo=fp16((w-hi)*2^12)
__global__ void k_pack(const float* __restrict__ src,
                       unsigned short* __restrict__ hi, unsigned short* __restrict__ lo,
                       int N, int K, int Kp, int total) {
    int idx = blockIdx.x*256 + threadIdx.x;
    if (idx >= total) return;
    int n = idx / Kp, k = idx - n*Kp;
    float v = (n < N && k < K) ? src[n*K + k] : 0.f;
    _Float16 h = (_Float16)v;
    float r1 = (v - (float)h) * 4096.0f;
    union { _Float16 h; unsigned short u; } ch, cl;
    ch.h = h; cl.h = (_Float16)r1;
    hi[idx] = ch.u;
    lo[idx] = cl.u;
}

// fc1 weight pack with (oc,pos) K-mapping: col k -> oc=k/124, pos=k%124;
// valid (oc<50, pos<121) -> src k' = oc*121+pos. Kp=6208.
__global__ void k_pack_fc1(const float* __restrict__ src,
                           unsigned short* __restrict__ hi, unsigned short* __restrict__ lo,
                           int total) {
    int idx = blockIdx.x*256 + threadIdx.x;
    if (idx >= total) return;
    int n = idx / 6208, k = idx - n*6208;
    int oc = k / 124, pos = k - oc*124;
    float v = (n < 500 && oc < 50 && pos < 121) ? src[n*6050 + oc*121 + pos] : 0.f;
    _Float16 h = (_Float16)v;
    float r1 = (v - (float)h) * 4096.0f;
    union { _Float16 h; unsigned short u; } ch, cl;
    ch.h = h; cl.h = (_Float16)r1;
    hi[idx] = ch.u;
    lo[idx] = cl.u;
}

// LIF scan over t for fc layers: s = hi_dot + 2^-12 * lo_dot, LIF recurrence.
__global__ __launch_bounds__(512) void k_lif_scan(
    const float* __restrict__ c0, size_t pstride,
    unsigned short* __restrict__ zout,
    int ld, int nvalid, float vth)
{
    int b = blockIdx.x;
    int n = threadIdx.x;
    float v = 0.f, cur = 0.f;
    for (int t = 0; t < T_STEPS; ++t) {
        size_t idx = (size_t)(t*BATCH + b)*ld + n;
        float s = __fadd_rn(c0[idx], __fmul_rn(S2LO, c0[idx + pstride]));
        float z = lif_update(s, v, cur, vth);
        zout[idx] = (n < nvalid && z > 0.5f) ? (unsigned short)0x3C00 : (unsigned short)0;
    }
}

// LI output cell scan: s = hi + 2^-12*lo; out[t] = decayed membrane (fp32)
__global__ void k_li(const float* __restrict__ c0, size_t pstride, float* __restrict__ out) {
    int g = blockIdx.x*64 + threadIdx.x;
    if (g >= 2560) return;
    int b = g / 10, n = g - b*10;
    float vo = 0.f, io = 0.f;
    for (int t = 0; t < T_STEPS; ++t) {
        size_t idx = (size_t)(t*BATCH + b)*16 + n;
        float s = __fadd_rn(c0[idx], __fmul_rn(S2LO, c0[idx + pstride]));
        float vd = __fadd_rn(vo, __fmul_rn(0.1f, __fsub_rn(io, vo)));
        out[(size_t)(t*BATCH + b)*10 + n] = vd;
        io = __fadd_rn(__fmul_rn(0.8f, io), s);
        vo = vd;
    }
}

extern "C" void kernel_launch(void* const* d_in, const int* in_sizes, int n_in,
                              void* d_out, int out_size, void* d_ws, size_t ws_size,
                              hipStream_t stream) {
    (void)in_sizes; (void)n_in; (void)out_size; (void)ws_size;
    const float* x   = (const float*)d_in[0];
    const float* w1  = (const float*)d_in[1];
    const float* w2  = (const float*)d_in[2];
    const float* wf1 = (const float*)d_in[3];
    const float* wf2 = (const float*)d_in[4];
    const float* wfo = (const float*)d_in[5];
    char* ws = (char*)d_ws;

    // ---- workspace layout (peak 182.5 MB < 208.4 MB proven writable) ----
    // phase A (conv): z1 [0, 127,139,840)  10240 x 6208 fp16
    //                 s0 [127,139,840, 169,082,880)  10240 x 4096 u8
    // phase B (fc1):  z1 live; overlay dead s0:
    //   W1 [127,139,840, 139,853,824) ; W2 [139,853,824, 140,378,112)
    //   Wo [140,378,112, 140,509,184) ; c2p[140,509,184, 182,452,224)
    // phase C (fc2+): z1 dead; low region, disjoint:
    //   z2 [0, 10,485,760) ; c3p [10,485,760, 31,457,280) ;
    //   z3 [31,457,280, 36,700,160) ; c4p [36,700,160, 38,010,880)
    unsigned short* z1    = (unsigned short*)(ws);
    unsigned char*  s0    = (unsigned char*)(ws + 127139840);
    unsigned short* W1hi  = (unsigned short*)(ws + 127139840);
    unsigned short* W2hi  = (unsigned short*)(ws + 139853824);
    unsigned short* Wohi  = (unsigned short*)(ws + 140378112);
    float*          c2p   = (float*)(ws + 140509184);
    unsigned short* z2    = (unsigned short*)(ws);
    float*          c3p   = (float*)(ws + 10485760);
    unsigned short* z3    = (unsigned short*)(ws + 31457280);
    float*          c4p   = (float*)(ws + 36700160);

    k_conv1<<<256, 576, 0, stream>>>(x, w1, s0);
    k_conv2<<<512, 256, 0, stream>>>(s0, w2, z1);

    k_pack_fc1<<<(3178496+255)/256, 256, 0, stream>>>(wf1, W1hi, W1hi+3178496, 3178496);
    k_pack<<<(131072+255)/256, 256, 0, stream>>>(wf2, W2hi, W2hi+131072, 200, 500, 512, 131072);
    k_pack<<<(32768+255)/256,  256, 0, stream>>>(wfo, Wohi, Wohi+32768,  10,  200, 256, 32768);

    k_gemm<<<dim3(80,4,2), 256, 0, stream>>>(z1, W1hi, c2p, 6208, 97, 512, 512,
                                             (size_t)3178496, (size_t)5242880);
    k_lif_scan<<<256, 512, 0, stream>>>(c2p, (size_t)5242880, z2, 512, 500, 0.1f);
    k_gemm<<<dim3(80,2,2), 256, 0, stream>>>(z2, W2hi, c3p, 512, 8, 256, 256,
                                             (size_t)131072, (size_t)2621440);
    k_lif_scan<<<256, 256, 0, stream>>>(c3p, (size_t)2621440, z3, 256, 200, 0.05f);
    k_gemm<<<dim3(80,1,2), 256, 0, stream>>>(z3, Wohi, c4p, 256, 4, 16, 16,
                                             (size_t)32768, (size_t)163840);
    k_li<<<40, 64, 0, stream>>>(c4p, (size_t)163840, (float*)d_out);
}

// Round 11
// 397.927 us; speedup vs baseline: 1.1551x; 1.1551x over previous
//
#include <hip/hip_runtime.h>
#include <hip/hip_bf16.h>

typedef _Float16 f16x8 __attribute__((ext_vector_type(8)));
typedef float f32x4  __attribute__((ext_vector_type(4)));
typedef unsigned short u16x4 __attribute__((ext_vector_type(4)));

#define T_STEPS 40
#define BATCH   256
#define S2LO    0.000244140625f   // 2^-12, exact

__device__ __forceinline__ unsigned short f2h_bits(float f) {
    union { _Float16 h; unsigned short u; } c; c.h = (_Float16)f; return c.u;
}

// norse LIF step, pinned to mul-then-add fp32 order.
__device__ __forceinline__ float lif_update(float inp, float& v, float& i, float vth) {
    float vd = __fadd_rn(v, __fmul_rn(0.1f, __fsub_rn(i, v)));
    float id = __fmul_rn(0.8f, i);
    float z  = (vd > vth) ? 1.0f : 0.0f;
    v = (vd > vth) ? 0.0f : vd;
    i = __fadd_rn(id, inp);
    return z;
}

__device__ __forceinline__ void llds16(const unsigned short* g, void* l) {
    __builtin_amdgcn_global_load_lds(
        (const __attribute__((address_space(1))) unsigned int*)g,
        (__attribute__((address_space(3))) unsigned int*)l, 16, 0, 0);
}

// ---------------------------------------------------------------------------
// Kernel 1 (v3): conv1 + LIF0 + 2x2 avgpool. One thread per pool cell
// (pos 0..168, oc 0..19): owns 4 pixels' LIF state across all t.
// 7 blocks x 512 threads per sample (grid 7 x 256) -> 7 blocks/CU.
// xl reads are 20-lane broadcasts (conflict-free); u8 stores contiguous.
// Output s0 u8 (pooled sum 0..4), row stride 4096: [pos169][ic24]+zero pad.
// ---------------------------------------------------------------------------
__global__ __launch_bounds__(512) void k_conv1(
    const float* __restrict__ x,             // [T,B,784] fp32
    const float* __restrict__ w1,            // [20,1,3,3] fp32
    unsigned char* __restrict__ s0)          // [T,B,4096] u8
{
    const int b    = blockIdx.y;
    const int tid  = threadIdx.x;
    const int cell = blockIdx.x*512 + tid;
    const bool active = cell < 3380;
    const int pos  = cell / 20;      // 0..168
    const int oc   = cell % 20;
    const int pr   = pos / 13, q = pos % 13;
    const int r0   = 2*pr, c0 = 2*q;

    __shared__ __align__(16) float xl[2][784];

    float wr[9];
    if (active) {
        #pragma unroll
        for (int j = 0; j < 9; ++j) wr[j] = w1[oc*9 + j];
    }
    float vs[2][2], is[2][2];
    #pragma unroll
    for (int dr = 0; dr < 2; ++dr)
        #pragma unroll
        for (int dc = 0; dc < 2; ++dc) { vs[dr][dc] = 0.f; is[dr][dc] = 0.f; }

    // prologue: stage t=0 into buffer 0
    if (tid < 196) {
        const float4* xs4 = (const float4*)(x + (size_t)b*784);
        *(float4*)&xl[0][tid*4] = xs4[tid];
    }

    for (int t = 0; t < T_STEPS; ++t) {
        __syncthreads();   // staging of t done; compute of t-1 done
        if (t + 1 < T_STEPS && tid < 196) {
            const float4* xs4 = (const float4*)(x + (size_t)((t+1)*BATCH + b)*784);
            *(float4*)&xl[(t+1)&1][tid*4] = xs4[tid];
        }
        const float* xc = xl[t&1];
        size_t base = (size_t)(t*BATCH + b) * 4096;

        if (active) {
            float tle[4][4];
            #pragma unroll
            for (int r = 0; r < 4; ++r)
                #pragma unroll
                for (int c = 0; c < 4; ++c)
                    tle[r][c] = xc[(r0 + r)*28 + c0 + c];
            int zsum = 0;
            #pragma unroll
            for (int dr = 0; dr < 2; ++dr)
                #pragma unroll
                for (int dc = 0; dc < 2; ++dc) {
                    float acc = 0.f;
                    #pragma unroll
                    for (int kr = 0; kr < 3; ++kr)
                        #pragma unroll
                        for (int kc = 0; kc < 3; ++kc)
                            acc += tle[dr+kr][dc+kc] * wr[kr*3+kc];
                    float z = lif_update(acc, vs[dr][dc], is[dr][dc], 0.2f);
                    zsum += (z > 0.5f) ? 1 : 0;
                }
            s0[base + (size_t)pos*24 + oc] = (unsigned char)zsum;
        } else {
            int p2 = cell - 3380;   // 0..203 (block 6 only)
            for (int idx = p2; idx < 716; idx += 204) {
                if (idx < 676) s0[base + (size_t)(idx >> 2)*24 + 20 + (idx & 3)] = 0;
                else           s0[base + 4056 + (idx - 676)] = 0;
            }
        }
    }
}

// ---------------------------------------------------------------------------
// Kernel 2: conv2 via fp16 MFMA, 2 blocks/sample (oc-split), double-buffered
// staging (u8 global->regs->fp16->ds_write_b128), one barrier/step. 2-plane
// weights (hi persistent in VGPR, scaled-lo from LDS) + LIF1 in VGPRs.
// z1 layout: oc-stride 124 -> aligned ushort4 stores.
// ---------------------------------------------------------------------------
__global__ __launch_bounds__(256, 2) void k_conv2(
    const unsigned char* __restrict__ s0,    // [T,B,4096] u8
    const float* __restrict__ w2,            // [50,20,3,3] fp32
    unsigned short* __restrict__ z1)         // [T,B,6208] fp16 spikes
{
    const int b    = blockIdx.x >> 1;
    const int half = blockIdx.x & 1;
    const int tid  = threadIdx.x;
    const int wv   = tid >> 6;
    const int lane = tid & 63;
    const int l15  = lane & 15;
    const int kg   = lane >> 4;
    const int wm   = wv;           // 4 m-waves x 32 pos

    __shared__ __align__(16) unsigned short w2h[32*232];
    __shared__ __align__(16) unsigned short w2m[32*232];
    __shared__ __align__(16) unsigned short sIn[2*4096];   // fp16 double buffer

    for (int s = tid; s < 32*232; s += 256) {
        int ocw = s / 232, kk = s % 232;
        int g = kk / 24, ic = kk % 24;
        int oc = half*32 + ocw;
        float val = 0.f;
        if (oc < 50 && g < 9 && ic < 20) val = w2[(oc*20 + ic)*9 + g];
        _Float16 h = (_Float16)val;
        float r1 = (val - (float)h) * 4096.0f;
        union { _Float16 h; unsigned short u; } ch, cm;
        ch.h = h; cm.h = (_Float16)r1;
        w2h[s] = ch.u;
        w2m[s] = cm.u;
    }

    f16x8 bfrH[2][7];
    int addrA[2][7];
    #pragma unroll
    for (int mt = 0; mt < 2; ++mt) {
        int pos = wm*32 + mt*16 + l15;
        #pragma unroll
        for (int kt = 0; kt < 7; ++kt) {
            int k = kt*32 + kg*8;
            int g = k / 24, o = k - g*24;
            if (pos <= 120 && g <= 8) {
                int in_idx = pos + 2*(pos/11) + 13*(g/3) + (g % 3);
                addrA[mt][kt] = in_idx*48 + o*2;
            } else addrA[mt][kt] = 8128;   // elem 4064: zeroed tail
        }
    }

    // stage t=0 into buffer 0 (u8 -> fp16*0.25, exact)
    {
        const unsigned char* srow = s0 + (size_t)(0*BATCH + b)*4096;
        uint4 raw = *(const uint4*)(srow + tid*16);
        unsigned short hv[16];
        #pragma unroll
        for (int w = 0; w < 4; ++w) {
            unsigned int u = ((const unsigned int*)&raw)[w];
            #pragma unroll
            for (int j = 0; j < 4; ++j)
                hv[w*4+j] = f2h_bits(0.25f * (float)((u >> (8*j)) & 0xFFu));
        }
        unsigned short* dst = sIn + tid*16;
        *(f16x8*)dst       = *(const f16x8*)&hv[0];
        *(f16x8*)(dst + 8) = *(const f16x8*)&hv[8];
    }
    __syncthreads();   // weights + t=0 staging visible

    #pragma unroll
    for (int nt = 0; nt < 2; ++nt) {
        int n = nt*16 + l15;
        #pragma unroll
        for (int kt = 0; kt < 7; ++kt)
            bfrH[nt][kt] = *(const f16x8*)&w2h[n*232 + kt*32 + kg*8];
    }

    float vst[2][2][4], ist[2][2][4];
    #pragma unroll
    for (int mt = 0; mt < 2; ++mt)
        #pragma unroll
        for (int nt = 0; nt < 2; ++nt)
            #pragma unroll
            for (int r = 0; r < 4; ++r) { vst[mt][nt][r] = 0.f; ist[mt][nt][r] = 0.f; }

    const f32x4 zero4 = {0.f, 0.f, 0.f, 0.f};

    for (int t = 0; t < T_STEPS; ++t) {
        if (t > 0) __syncthreads();

        uint4 raw;
        if (t + 1 < T_STEPS)
            raw = *(const uint4*)(s0 + (size_t)((t+1)*BATCH + b)*4096 + tid*16);

        const char* curB = (const char*)(sIn + (t&1)*4096);

        f32x4 acch[2][2], accl[2][2];
        #pragma unroll
        for (int mt = 0; mt < 2; ++mt)
            #pragma unroll
            for (int nt = 0; nt < 2; ++nt) { acch[mt][nt] = zero4; accl[mt][nt] = zero4; }

        #pragma unroll
        for (int kt = 0; kt < 7; ++kt) {
            f16x8 bm[2];
            #pragma unroll
            for (int nt = 0; nt < 2; ++nt) {
                int n = nt*16 + l15, k = kt*32 + kg*8;
                bm[nt] = *(const f16x8*)&w2m[n*232 + k];
            }
            #pragma unroll
            for (int mt = 0; mt < 2; ++mt) {
                f16x8 a = *(const f16x8*)(curB + addrA[mt][kt]);
                #pragma unroll
                for (int nt = 0; nt < 2; ++nt) {
                    acch[mt][nt] = __builtin_amdgcn_mfma_f32_16x16x32_f16(
                        a, bfrH[nt][kt], acch[mt][nt], 0, 0, 0);
                    accl[mt][nt] = __builtin_amdgcn_mfma_f32_16x16x32_f16(
                        a, bm[nt], accl[mt][nt], 0, 0, 0);
                }
            }
        }

        size_t rowoff = (size_t)(t*BATCH + b) * 6208;
        #pragma unroll
        for (int mt = 0; mt < 2; ++mt) {
            int posb = wm*32 + mt*16 + kg*4;
            #pragma unroll
            for (int nt = 0; nt < 2; ++nt) {
                int ocn = half*32 + nt*16 + l15;
                u16x4 pack;
                #pragma unroll
                for (int r = 0; r < 4; ++r) {
                    float inp = __fadd_rn(acch[mt][nt][r], __fmul_rn(S2LO, accl[mt][nt][r]));
                    float z = lif_update(inp, vst[mt][nt][r], ist[mt][nt][r], 0.2f);
                    int pos = posb + r;
                    pack[r] = (pos <= 120 && z > 0.5f) ? (unsigned short)0x3C00 : (unsigned short)0;
                }
                if (ocn < 50 && posb < 121)
                    *(u16x4*)(z1 + rowoff + ocn*124 + posb) = pack;
            }
        }
        if (half == 0 && tid < 8) z1[rowoff + 6200 + tid] = 0;

        if (t + 1 < T_STEPS) {
            unsigned short hv[16];
            #pragma unroll
            for (int w = 0; w < 4; ++w) {
                unsigned int u = ((const unsigned int*)&raw)[w];
                #pragma unroll
                for (int j = 0; j < 4; ++j)
                    hv[w*4+j] = f2h_bits(0.25f * (float)((u >> (8*j)) & 0xFFu));
            }
            unsigned short* dst = sIn + ((t+1)&1)*4096 + tid*16;
            *(f16x8*)dst       = *(const f16x8*)&hv[0];
            *(f16x8*)(dst + 8) = *(const f16x8*)&hv[8];
        }
    }
}

// ---------------------------------------------------------------------------
// MFMA GEMM (fp16), m97 2-buffer, global_load_lds w16, XOR-swizzled LDS.
// blockIdx.z selects weight plane. 128x128 tile, BK=64.
// ---------------------------------------------------------------------------
__global__ __launch_bounds__(256, 3) void k_gemm(
    const unsigned short* __restrict__ A,
    const unsigned short* __restrict__ B0,
    float* __restrict__ C0,
    int Kp, int kiters, int ldc, int nstore,
    size_t strideB, size_t strideC)
{
    __shared__ __align__(16) unsigned short As[128*64];
    __shared__ __align__(16) unsigned short Bs[128*64];
    const unsigned short* B = B0 + (size_t)blockIdx.z * strideB;
    float* C = C0 + (size_t)blockIdx.z * strideC;

    const int tid  = threadIdx.x;
    const int lane = tid & 63;
    const int wv   = tid >> 6;
    const int wm   = wv & 1, wn = wv >> 1;
    const int l15  = lane & 15, kg = lane >> 4;
    const int mbase = blockIdx.x * 128;
    const int nbase = blockIdx.y * 128;

    const f32x4 zero4 = {0.f, 0.f, 0.f, 0.f};
    f32x4 acc[4][4];
    #pragma unroll
    for (int mt = 0; mt < 4; ++mt)
        #pragma unroll
        for (int nt = 0; nt < 4; ++nt) acc[mt][nt] = zero4;

    const int rowA = tid >> 3;                        // 0..31
    const int sw   = (((tid & 7) ^ (rowA & 7))) * 8;  // xor-swizzled chunk (elems)
    char* ldsA = (char*)As + (size_t)wv*1024;
    char* ldsB = (char*)Bs + (size_t)wv*1024;

    for (int ki = 0; ki < kiters; ++ki) {
        int kb = ki * 64;
        #pragma unroll
        for (int c = 0; c < 4; ++c) {
            int row = c*32 + rowA;
            llds16(A + (size_t)(mbase + row)*Kp + kb + sw, ldsA + c*4096);
            llds16(B + (size_t)(nbase + row)*Kp + kb + sw, ldsB + c*4096);
        }
        __syncthreads();
        #pragma unroll
        for (int kt = 0; kt < 2; ++kt) {
            f16x8 bfv[4], afv[4];
            #pragma unroll
            for (int nt = 0; nt < 4; ++nt) {
                int rb = wn*64 + nt*16 + l15;
                int ch = ((kt*4 + kg) ^ (rb & 7)) * 8;
                bfv[nt] = *(const f16x8*)&Bs[rb*64 + ch];
            }
            #pragma unroll
            for (int mt = 0; mt < 4; ++mt) {
                int ra = wm*64 + mt*16 + l15;
                int ch = ((kt*4 + kg) ^ (ra & 7)) * 8;
                afv[mt] = *(const f16x8*)&As[ra*64 + ch];
            }
            #pragma unroll
            for (int mt = 0; mt < 4; ++mt)
                #pragma unroll
                for (int nt = 0; nt < 4; ++nt)
                    acc[mt][nt] = __builtin_amdgcn_mfma_f32_16x16x32_f16(
                        afv[mt], bfv[nt], acc[mt][nt], 0, 0, 0);
        }
        __syncthreads();
    }

    #pragma unroll
    for (int mt = 0; mt < 4; ++mt) {
        int m0 = mbase + wm*64 + mt*16 + kg*4;
        #pragma unroll
        for (int nt = 0; nt < 4; ++nt) {
            int n = nbase + wn*64 + nt*16 + l15;
            if (n < nstore) {
                #pragma unroll
                for (int r = 0; r < 4; ++r)
                    C[(size_t)(m0 + r)*ldc + n] = acc[mt][nt][r];
            }
        }
    }
}

// Pack fp32 weights [N,K] -> zero-padded fp16 planes: hi=fp16(w), lo=fp16((w-hi)*2^12)
__global__ void k_pack(const float* __restrict__ src,
                       unsigned short* __restrict__ hi, unsigned short* __restrict__ lo,
                       int N, int K, int Kp, int total) {
    int idx = blockIdx.x*256 + threadIdx.x;
    if (idx >= total) return;
    int n = idx / Kp, k = idx - n*Kp;
    float v = (n < N && k < K) ? src[n*K + k] : 0.f;
    _Float16 h = (_Float16)v;
    float r1 = (v - (float)h) * 4096.0f;
    union { _Float16 h; unsigned short u; } ch, cl;
    ch.h = h; cl.h = (_Float16)r1;
    hi[idx] = ch.u;
    lo[idx] = cl.u;
}

// fc1 weight pack with (oc,pos) K-mapping: col k -> oc=k/124, pos=k%124;
// valid (oc<50, pos<121) -> src k' = oc*121+pos. Kp=6208.
__global__ void k_pack_fc1(const float* __restrict__ src,
                           unsigned short* __restrict__ hi, unsigned short* __restrict__ lo,
                           int total) {
    int idx = blockIdx.x*256 + threadIdx.x;
    if (idx >= total) return;
    int n = idx / 6208, k = idx - n*6208;
    int oc = k / 124, pos = k - oc*124;
    float v = (n < 500 && oc < 50 && pos < 121) ? src[n*6050 + oc*121 + pos] : 0.f;
    _Float16 h = (_Float16)v;
    float r1 = (v - (float)h) * 4096.0f;
    union { _Float16 h; unsigned short u; } ch, cl;
    ch.h = h; cl.h = (_Float16)r1;
    hi[idx] = ch.u;
    lo[idx] = cl.u;
}

// LIF scan over t for fc layers: s = hi_dot + 2^-12 * lo_dot, LIF recurrence.
__global__ __launch_bounds__(512) void k_lif_scan(
    const float* __restrict__ c0, size_t pstride,
    unsigned short* __restrict__ zout,
    int ld, int nvalid, float vth)
{
    int b = blockIdx.x;
    int n = threadIdx.x;
    float v = 0.f, cur = 0.f;
    for (int t = 0; t < T_STEPS; ++t) {
        size_t idx = (size_t)(t*BATCH + b)*ld + n;
        float s = __fadd_rn(c0[idx], __fmul_rn(S2LO, c0[idx + pstride]));
        float z = lif_update(s, v, cur, vth);
        zout[idx] = (n < nvalid && z > 0.5f) ? (unsigned short)0x3C00 : (unsigned short)0;
    }
}

// LI output cell scan: s = hi + 2^-12*lo; out[t] = decayed membrane (fp32)
__global__ void k_li(const float* __restrict__ c0, size_t pstride, float* __restrict__ out) {
    int g = blockIdx.x*64 + threadIdx.x;
    if (g >= 2560) return;
    int b = g / 10, n = g - b*10;
    float vo = 0.f, io = 0.f;
    for (int t = 0; t < T_STEPS; ++t) {
        size_t idx = (size_t)(t*BATCH + b)*16 + n;
        float s = __fadd_rn(c0[idx], __fmul_rn(S2LO, c0[idx + pstride]));
        float vd = __fadd_rn(vo, __fmul_rn(0.1f, __fsub_rn(io, vo)));
        out[(size_t)(t*BATCH + b)*10 + n] = vd;
        io = __fadd_rn(__fmul_rn(0.8f, io), s);
        vo = vd;
    }
}

extern "C" void kernel_launch(void* const* d_in, const int* in_sizes, int n_in,
                              void* d_out, int out_size, void* d_ws, size_t ws_size,
                              hipStream_t stream) {
    (void)in_sizes; (void)n_in; (void)out_size; (void)ws_size;
    const float* x   = (const float*)d_in[0];
    const float* w1  = (const float*)d_in[1];
    const float* w2  = (const float*)d_in[2];
    const float* wf1 = (const float*)d_in[3];
    const float* wf2 = (const float*)d_in[4];
    const float* wfo = (const float*)d_in[5];
    char* ws = (char*)d_ws;

    // ---- workspace layout (peak 182.5 MB < 208.4 MB proven writable) ----
    // phase A (conv): z1 [0, 127,139,840)  10240 x 6208 fp16
    //                 s0 [127,139,840, 169,082,880)  10240 x 4096 u8
    // phase B (fc1):  z1 live; overlay dead s0:
    //   W1 [127,139,840, 139,853,824) ; W2 [139,853,824, 140,378,112)
    //   Wo [140,378,112, 140,509,184) ; c2p[140,509,184, 182,452,224)
    // phase C (fc2+): z1 dead; low region, disjoint:
    //   z2 [0, 10,485,760) ; c3p [10,485,760, 31,457,280) ;
    //   z3 [31,457,280, 36,700,160) ; c4p [36,700,160, 38,010,880)
    unsigned short* z1    = (unsigned short*)(ws);
    unsigned char*  s0    = (unsigned char*)(ws + 127139840);
    unsigned short* W1hi  = (unsigned short*)(ws + 127139840);
    unsigned short* W2hi  = (unsigned short*)(ws + 139853824);
    unsigned short* Wohi  = (unsigned short*)(ws + 140378112);
    float*          c2p   = (float*)(ws + 140509184);
    unsigned short* z2    = (unsigned short*)(ws);
    float*          c3p   = (float*)(ws + 10485760);
    unsigned short* z3    = (unsigned short*)(ws + 31457280);
    float*          c4p   = (float*)(ws + 36700160);

    k_conv1<<<dim3(7, 256), 512, 0, stream>>>(x, w1, s0);
    k_conv2<<<512, 256, 0, stream>>>(s0, w2, z1);

    k_pack_fc1<<<(3178496+255)/256, 256, 0, stream>>>(wf1, W1hi, W1hi+3178496, 3178496);
    k_pack<<<(131072+255)/256, 256, 0, stream>>>(wf2, W2hi, W2hi+131072, 200, 500, 512, 131072);
    k_pack<<<(32768+255)/256,  256, 0, stream>>>(wfo, Wohi, Wohi+32768,  10,  200, 256, 32768);

    k_gemm<<<dim3(80,4,2), 256, 0, stream>>>(z1, W1hi, c2p, 6208, 97, 512, 512,
                                             (size_t)3178496, (size_t)5242880);
    k_lif_scan<<<256, 512, 0, stream>>>(c2p, (size_t)5242880, z2, 512, 500, 0.1f);
    k_gemm<<<dim3(80,2,2), 256, 0, stream>>>(z2, W2hi, c3p, 512, 8, 256, 256,
                                             (size_t)131072, (size_t)2621440);
    k_lif_scan<<<256, 256, 0, stream>>>(c3p, (size_t)2621440, z3, 256, 200, 0.05f);
    k_gemm<<<dim3(80,1,2), 256, 0, stream>>>(z3, Wohi, c4p, 256, 4, 16, 16,
                                             (size_t)32768, (size_t)163840);
    k_li<<<40, 64, 0, stream>>>(c4p, (size_t)163840, (float*)d_out);
}